// Round 4
// baseline (277.867 us; speedup 1.0000x reference)
//
#include <hip/hip_runtime.h>

// ---------------------------------------------------------------------------
// HVIN: maxpool -> composite5x5 conv -> VI scan (32^2, SPLIT across pair) ->
//       upsample -> composite5x5 conv -> VI scan (64^2, split across pair)
//       -> final conv + BN + dueling head
//
// Grid: 256 blocks x 1024 threads. Pair (b, b^8) on the SAME XCD handles
// image n = (b&7)|((b>>4)<<3); half = (b>>3)&1. Inner VI: rows [16h,16h+16);
// outer VI: rows [32h,32h+32). Per-step boundary-row halo exchange through
// global memory with a monotone per-block flag (release/acquire, agent
// scope). The sender wave contains the flag thread, so the release-store's
// vmcnt drain publishes the halo: ONE __syncthreads per VI step.
// Flags: inner steps 1..15, v1-exchange 16, outer 17..31, vbar 32.
//
// ws float layout:
//   [0..49]     WeffO   [64..225]  GO    [256..305] WeffI   [320..481] GI
//   [512..521]  bn_sum  [528..537] bn_sumsq
//   [544..1823] q_pix[128][10]
//   ints [1824..2079]: flags[256]  (zeroed by k_precomp each launch)
//   [2176..]    halo[256 blocks][3 slots][64]   (stride 192)
// ---------------------------------------------------------------------------

#define NEG_BIG (-3.402823466e38f)
#define SCOPE_AGENT __HIP_MEMORY_SCOPE_AGENT

__global__ void k_precomp(const float* __restrict__ conv_h_w,
                          const float* __restrict__ conv_r_w,
                          const float* __restrict__ vi_h_w,
                          const float* __restrict__ vi_r_w,
                          float* __restrict__ ws) {
    __shared__ float sG[2][162];
    int t = threadIdx.x; // 512 threads
    if (t < 324) {
        int set = t / 162;      // 0 = outer, 1 = inner
        int e   = t % 162;
        int ax = e % 3;  int e1 = e / 3;
        int ay = e1 % 3; int e2 = e1 / 3;
        int i  = e2 % 2; int e3 = e2 / 2;
        int bx = e3 % 3; int by = e3 / 3;
        const float* Wh = set ? vi_h_w : conv_h_w;
        const float* Wr = set ? vi_r_w : conv_r_w;
        float acc = 0.f;
        for (int c = 0; c < 150; ++c)
            acc += Wr[(c*3+by)*3+bx] * Wh[((c*2+i)*3+ay)*3+ax];
        sG[set][e] = acc;
        ws[(set ? 320 : 64) + e] = acc;
    }
    if (t >= 480 && t < 512) ws[512 + (t - 480)] = 0.f;  // zero BN accumulators
    if (t < 256) ((int*)ws)[1824 + t] = 0;               // zero pair-sync flags
    __syncthreads();
    if (t < 100) {
        int set = t / 50;
        int e   = t % 50;
        int i  = e / 25;
        int oy = (e % 25) / 5;
        int ox = e % 5;
        float acc = 0.f;
        for (int by = 0; by < 3; ++by) {
            int ay = oy - by; if (ay < 0 || ay > 2) continue;
            for (int bx = 0; bx < 3; ++bx) {
                int ax = ox - bx; if (ax < 0 || ax > 2) continue;
                acc += sG[set][(((by*3+bx)*2+i)*3+ay)*3+ax];
            }
        }
        ws[(set ? 256 : 0) + e] = acc;
    }
}

// ---- inner VI step: 512 threads compute own 16 rows; exchange boundary ----
#define ISTEP(VC, VN, K)                                                      \
  {                                                                           \
    const float* wk_ = vi_q_ws + (K) * 180;                                   \
    float m_ = NEG_BIG;                                                       \
    if (t < 512) {                                                            \
      float pv_[3][3];                                                        \
      _Pragma("unroll") for (int dy = 0; dy < 3; ++dy)                        \
        _Pragma("unroll") for (int dx = 0; dx < 3; ++dx)                      \
          pv_[dy][dx] = VC[ilr + dy][iix + dx];                               \
      for (int ch = 0; ch < 10; ++ch) {                                       \
        const float* wc_ = wk_ + ch * 18;                                     \
        float q_ = 0.f;                                                       \
        _Pragma("unroll") for (int ky = 0; ky < 3; ++ky)                      \
          _Pragma("unroll") for (int kx = 0; kx < 3; ++kx)                    \
            q_ += wc_[ky*3+kx] * pr_[ky][kx] + wc_[9+ky*3+kx] * pv_[ky][kx];  \
        m_ = fmaxf(m_, q_);                                                   \
      }                                                                       \
      VN[1 + ilr][1 + iix] = m_;                                              \
      isum += m_;                                                             \
    }                                                                         \
    if ((K) < 15) {                                                           \
      if (t >= sLo && t < sLo + 32)                                           \
        __hip_atomic_store(ghMine + ((K)&1)*64 + (t - sLo), m_,               \
                           __ATOMIC_RELAXED, SCOPE_AGENT);                    \
      if (t == sLo) {                                                         \
        __hip_atomic_store(flagMine, (K) + 1, __ATOMIC_RELEASE, SCOPE_AGENT); \
        int spins_ = 0;                                                       \
        while (__hip_atomic_load(flagPart, __ATOMIC_ACQUIRE, SCOPE_AGENT) < (K)+1) \
          if (++spins_ > (1 << 27)) break;                                    \
      }                                                                       \
      if (t >= rLo && t < rLo + 32)                                           \
        VN[gRowI][1 + (t - rLo)] =                                            \
          __hip_atomic_load(ghPart + ((K)&1)*64 + (t - rLo),                  \
                            __ATOMIC_RELAXED, SCOPE_AGENT);                   \
    }                                                                         \
    __syncthreads();                                                          \
  }

// ---- outer VI step: wave rp handles local row pair (2pp, 2pp+1) ----------
#define OSTEP(VC, VN, K)                                                      \
  {                                                                           \
    const float* wk_ = conv_q_ws + (K) * 270;                                 \
    float pm_[4][3], pq_[4][3], pv_[4][3];                                    \
    _Pragma("unroll") for (int dy = 0; dy < 4; ++dy)                          \
      _Pragma("unroll") for (int dx = 0; dx < 3; ++dx) {                      \
        pm_[dy][dx] = sm[2*pp + dy][oc + dx];                                 \
        pq_[dy][dx] = sr[2*pp + dy][oc + dx];                                 \
        pv_[dy][dx] = VC[2*pp + dy][oc + dx];                                 \
      }                                                                       \
    float vm0_ = NEG_BIG, vm1_ = NEG_BIG;                                     \
    for (int ch = 0; ch < 10; ++ch) {                                         \
      const float* wc_ = wk_ + ch * 27;                                       \
      float q0_ = 0.f, q1_ = 0.f;                                             \
      _Pragma("unroll") for (int ky = 0; ky < 3; ++ky)                        \
        _Pragma("unroll") for (int kx = 0; kx < 3; ++kx) {                    \
          float wm_ = wc_[ky*3+kx], wr_ = wc_[9+ky*3+kx], wv_ = wc_[18+ky*3+kx]; \
          q0_ += wm_*pm_[ky][kx]   + wr_*pq_[ky][kx]   + wv_*pv_[ky][kx];     \
          q1_ += wm_*pm_[ky+1][kx] + wr_*pq_[ky+1][kx] + wv_*pv_[ky+1][kx];   \
        }                                                                     \
      vm0_ = fmaxf(vm0_, q0_); vm1_ = fmaxf(vm1_, q1_);                       \
    }                                                                         \
    VN[1+2*pp][1+oc] = vm0_;                                                  \
    VN[2+2*pp][1+oc] = vm1_;                                                  \
    os0 += vm0_; os1 += vm1_;                                                 \
    if ((K) < 15 && rp == 0) {                                                \
      __hip_atomic_store(ghMine + ((K)&1)*64 + oc, half ? vm0_ : vm1_,        \
                         __ATOMIC_RELAXED, SCOPE_AGENT);                      \
      if (t == 0) {                                                           \
        __hip_atomic_store(flagMine, (K) + 17, __ATOMIC_RELEASE, SCOPE_AGENT);\
        int spins_ = 0;                                                       \
        while (__hip_atomic_load(flagPart, __ATOMIC_ACQUIRE, SCOPE_AGENT) < (K)+17) \
          if (++spins_ > (1 << 27)) break;                                    \
      }                                                                       \
      VN[gRowO][1+oc] =                                                       \
        __hip_atomic_load(ghPart + ((K)&1)*64 + oc,                           \
                          __ATOMIC_RELAXED, SCOPE_AGENT);                     \
    }                                                                         \
    __syncthreads();                                                          \
  }

__global__ __launch_bounds__(1024) void k_main(
    const float* __restrict__ Xg,        // [128][2][64][64]
    const int*   __restrict__ S1,
    const int*   __restrict__ S2,
    const float* __restrict__ conv_q_ws, // [16][10][3][3][3]
    const float* __restrict__ vi_q_ws,   // [16][10][2][3][3]
    const float* __restrict__ ws,        // composites (read-only)
    float*       __restrict__ wsm)       // BN accum + qpix + flags + halo
{
    __shared__ float sX[2][64][64];
    __shared__ float sX1[2][32][32];
    __shared__ float sr1[18][34];        // r1 rows [gi0-1, gi0+16], ring-padded
    __shared__ float sva[18][34];        // inner v ping
    __shared__ float svb[18][34];        // inner v pong; later v1
    __shared__ float sm[34][66];         // rows gr0-1..gr0+32, ring-padded
    __shared__ float sr[34][66];
    __shared__ float sV0[34][66];
    __shared__ float sV1[34][66];
    __shared__ float sRed[10][2];
    __shared__ float sPad[512];          // force LDS > 80 KB: 1 block/CU,
                                         // guarantees pair co-residency

    const int bid  = blockIdx.x;
    const int half = (bid >> 3) & 1;
    const int n    = (bid & 7) | ((bid >> 4) << 3);  // pair (b, b^8) same XCD
    const int gr0  = half << 5;          // first own outer row
    const int gi0  = half << 4;          // first own inner row
    const int t    = threadIdx.x;

    int*   flagMine = (int*)wsm + 1824 + bid;
    int*   flagPart = (int*)wsm + 1824 + (bid ^ 8);
    float* ghMine   = wsm + 2176 + bid * 192;
    float* ghPart   = wsm + 2176 + (bid ^ 8) * 192;

    // inner exchange roles (sender wave contains flag thread and readers)
    const int sLo   = half ? 0 : 480;    // sender threads [sLo, sLo+32)
    const int rLo   = half ? 32 : 448;   // ghost-reader threads
    const int gRowI = half ? 0 : 17;     // inner ghost array row
    const int gRowO = half ? 0 : 33;     // outer ghost array row

    // ---- zero-init ring/halo arrays ----
    {
        float* z;
        z = &sr1[0][0]; for (int i = t; i < 612;  i += 1024) z[i] = 0.f;
        z = &sva[0][0]; for (int i = t; i < 612;  i += 1024) z[i] = 0.f;
        z = &svb[0][0]; for (int i = t; i < 612;  i += 1024) z[i] = 0.f;
        z = &sm[0][0];  for (int i = t; i < 2244; i += 1024) z[i] = 0.f;
        z = &sr[0][0];  for (int i = t; i < 2244; i += 1024) z[i] = 0.f;
        z = &sV0[0][0]; for (int i = t; i < 2244; i += 1024) z[i] = 0.f;
        z = &sV1[0][0]; for (int i = t; i < 2244; i += 1024) z[i] = 0.f;
        if (t < 512) sPad[t] = 0.f;
    }
    // ---- P0: load full X (coalesced float4) ----
    {
        const float4* src = (const float4*)(Xg + (size_t)n * 8192);
        float4* dst = (float4*)&sX[0][0][0];
        dst[t] = src[t];
        dst[t + 1024] = src[t + 1024];
    }
    __syncthreads();

    // ---- P1: maxpool 2x2 -> sX1 ----
    for (int idx = t; idx < 2048; idx += 1024) {
        int c = idx >> 10;
        int y = (idx >> 5) & 31;
        int x = idx & 31;
        float a0 = sX[c][2*y][2*x],   a1 = sX[c][2*y][2*x+1];
        float a2 = sX[c][2*y+1][2*x], a3 = sX[c][2*y+1][2*x+1];
        sX1[c][y][x] = fmaxf(fmaxf(a0, a1), fmaxf(a2, a3));
    }
    __syncthreads();

    // ---- P2: r1 rows [gi0-1, gi0+16] (own + halo; locally computed) ----
    if (t < 576) {
        const float* WeffI = ws + 256;
        const float* GI    = ws + 320;
        int ar = t >> 5, x = t & 31;
        int g  = gi0 + ar - 1;
        if ((unsigned)g < 32u) {
            float acc = 0.f;
            for (int i = 0; i < 2; ++i)
                for (int oy = 0; oy < 5; ++oy) {
                    int yy = g + oy - 2; if (yy < 0 || yy >= 32) continue;
                    for (int ox = 0; ox < 5; ++ox) {
                        int xx = x + ox - 2; if (xx < 0 || xx >= 32) continue;
                        acc += WeffI[i*25 + oy*5 + ox] * sX1[i][yy][xx];
                    }
                }
            if (g == 0 || g == 31 || x == 0 || x == 31) {
                float corr = 0.f;
                for (int by = 0; by < 3; ++by)
                    for (int bx = 0; bx < 3; ++bx) {
                        int qy = g + by - 1, qx = x + bx - 1;
                        if (qy >= 0 && qy < 32 && qx >= 0 && qx < 32) continue;
                        const float* Gb = GI + (by*3+bx)*18;
                        for (int i = 0; i < 2; ++i)
                            for (int ay = 0; ay < 3; ++ay) {
                                int yy2 = qy + ay - 1; if (yy2 < 0 || yy2 >= 32) continue;
                                for (int ax = 0; ax < 3; ++ax) {
                                    int xx2 = qx + ax - 1; if (xx2 < 0 || xx2 >= 32) continue;
                                    corr += Gb[i*9 + ay*3 + ax] * sX1[i][yy2][xx2];
                                }
                            }
                    }
                acc -= corr;
            }
            sr1[ar][1+x] = acc;
        }
    }
    __syncthreads();

    // ---- P3: inner VI loop (16 steps, own 16 rows, halo exchange) ----
    const int ilr = t >> 5;   // local row (t < 512)
    const int iix = t & 31;   // col
    float pr_[3][3];
    if (t < 512) {
        #pragma unroll
        for (int dy = 0; dy < 3; ++dy)
            #pragma unroll
            for (int dx = 0; dx < 3; ++dx)
                pr_[dy][dx] = sr1[ilr+dy][iix+dx];
    }
    float isum = 0.f;
    for (int k2 = 0; k2 < 8; ++k2) {
        ISTEP(sva, svb, 2*k2);
        ISTEP(svb, sva, 2*k2+1);
    }
    // v1 = isum/4 into svb; exchange boundary row (slot 128, flag 16)
    {
        float v1v = isum * 0.25f;
        if (t < 512) svb[1+ilr][1+iix] = v1v;
        if (t >= sLo && t < sLo + 32)
            __hip_atomic_store(ghMine + 128 + (t - sLo), v1v,
                               __ATOMIC_RELAXED, SCOPE_AGENT);
        if (t == sLo) {
            __hip_atomic_store(flagMine, 16, __ATOMIC_RELEASE, SCOPE_AGENT);
            int spins = 0;
            while (__hip_atomic_load(flagPart, __ATOMIC_ACQUIRE, SCOPE_AGENT) < 16)
                if (++spins > (1 << 27)) break;
        }
        if (t >= rLo && t < rLo + 32)
            svb[gRowI][1 + (t - rLo)] =
                __hip_atomic_load(ghPart + 128 + (t - rLo),
                                  __ATOMIC_RELAXED, SCOPE_AGENT);
    }
    __syncthreads();

    // ---- P4+P5: m = upsample(v1), r = composite conv(X); rows gr0-1..gr0+32
    {
        const float* WeffO = ws;
        const float* GO    = ws + 64;
        int c = t & 63;
        for (int ar = t >> 6; ar < 34; ar += 16) {
            int g = gr0 + ar - 1;
            if ((unsigned)g < 64u) {
                // bilinear upsample 32->64 at (g, c); v1 local idx = y - gi0 + 1
                int y0, y1; float wy0, wy1;
                if ((g & 1) == 0) { y1 = g >> 1; y0 = (y1 > 0) ? y1 - 1 : 0; wy1 = 0.75f; wy0 = 0.25f; }
                else              { y0 = g >> 1; y1 = (y0 < 31) ? y0 + 1 : 31; wy0 = 0.75f; wy1 = 0.25f; }
                int xa, xb; float wx0, wx1;
                if ((c & 1) == 0) { xb = c >> 1; xa = (xb > 0) ? xb - 1 : 0; wx1 = 0.75f; wx0 = 0.25f; }
                else               { xa = c >> 1; xb = (xa < 31) ? xa + 1 : 31; wx0 = 0.75f; wx1 = 0.25f; }
                int l0 = y0 - gi0 + 1, l1 = y1 - gi0 + 1;
                sm[ar][1+c] = wy0 * (wx0 * svb[l0][1+xa] + wx1 * svb[l0][1+xb])
                            + wy1 * (wx0 * svb[l1][1+xa] + wx1 * svb[l1][1+xb]);
                // composite 5x5 conv of X at (g, c)
                float acc = 0.f;
                for (int i = 0; i < 2; ++i)
                    for (int oy = 0; oy < 5; ++oy) {
                        int yy = g + oy - 2; if (yy < 0 || yy >= 64) continue;
                        for (int ox = 0; ox < 5; ++ox) {
                            int xx = c + ox - 2; if (xx < 0 || xx >= 64) continue;
                            acc += WeffO[i*25 + oy*5 + ox] * sX[i][yy][xx];
                        }
                    }
                if (g == 0 || g == 63 || c == 0 || c == 63) {
                    float corr = 0.f;
                    for (int by = 0; by < 3; ++by)
                        for (int bx = 0; bx < 3; ++bx) {
                            int qy = g + by - 1, qx = c + bx - 1;
                            if (qy >= 0 && qy < 64 && qx >= 0 && qx < 64) continue;
                            const float* Gb = GO + (by*3+bx)*18;
                            for (int i = 0; i < 2; ++i)
                                for (int ay = 0; ay < 3; ++ay) {
                                    int yy2 = qy + ay - 1; if (yy2 < 0 || yy2 >= 64) continue;
                                    for (int ax = 0; ax < 3; ++ax) {
                                        int xx2 = qx + ax - 1; if (xx2 < 0 || xx2 >= 64) continue;
                                        corr += Gb[i*9 + ay*3 + ax] * sX[i][yy2][xx2];
                                    }
                                }
                        }
                    acc -= corr;
                }
                sr[ar][1+c] = acc;
            }
        }
    }
    __syncthreads();

    // ---- P6: outer VI loop (16 steps). Wave 0 owns the boundary row pair.
    const int rp = t >> 6;                   // wave id
    const int pp = half ? rp : (15 - rp);    // local row-pair index
    const int oc = t & 63;                   // col
    float os0 = 0.f, os1 = 0.f;

    for (int k2 = 0; k2 < 8; ++k2) {
        OSTEP(sV0, sV1, 2*k2);
        OSTEP(sV1, sV0, 2*k2+1);
    }

    // ---- vbar = sum/16 into sV1; exchange its halo (slot 128, flag 32) ----
    {
        float vb0 = os0 * 0.0625f, vb1 = os1 * 0.0625f;
        sV1[1+2*pp][1+oc] = vb0;
        sV1[2+2*pp][1+oc] = vb1;
        if (rp == 0) {
            __hip_atomic_store(ghMine + 128 + oc, half ? vb0 : vb1,
                               __ATOMIC_RELAXED, SCOPE_AGENT);
            if (t == 0) {
                __hip_atomic_store(flagMine, 32, __ATOMIC_RELEASE, SCOPE_AGENT);
                int spins = 0;
                while (__hip_atomic_load(flagPart, __ATOMIC_ACQUIRE, SCOPE_AGENT) < 32)
                    if (++spins > (1 << 27)) break;
            }
            sV1[gRowO][1+oc] =
                __hip_atomic_load(ghPart + 128 + oc, __ATOMIC_RELAXED, SCOPE_AGENT);
        }
        if (t >= 64 && t < 84) ((float*)sRed)[t - 64] = 0.f;
    }
    __syncthreads();

    // ---- P7: final conv (w15) on {m, r, vbar} + BN stats + (S1,S2) pick ----
    {
        const float* wk = conv_q_ws + 15 * 270;
        float pm[4][3], pq[4][3], pv[4][3];
        #pragma unroll
        for (int dy = 0; dy < 4; ++dy)
            #pragma unroll
            for (int dx = 0; dx < 3; ++dx) {
                pm[dy][dx] = sm[2*pp+dy][oc+dx];
                pq[dy][dx] = sr[2*pp+dy][oc+dx];
                pv[dy][dx] = sV1[2*pp+dy][oc+dx];
            }
        int sy = S1[n], sx = S2[n];
        int g0 = gr0 + 2*pp, g1 = g0 + 1;
        float* qpix = wsm + 544 + n * 10;
        for (int ch = 0; ch < 10; ++ch) {
            const float* wc = wk + ch * 27;
            float q0 = 0.f, q1 = 0.f;
            #pragma unroll
            for (int ky = 0; ky < 3; ++ky)
                #pragma unroll
                for (int kx = 0; kx < 3; ++kx) {
                    float wm = wc[ky*3+kx];
                    float wr = wc[9  + ky*3+kx];
                    float wv = wc[18 + ky*3+kx];
                    q0 += wm * pm[ky][kx]   + wr * pq[ky][kx]   + wv * pv[ky][kx];
                    q1 += wm * pm[ky+1][kx] + wr * pq[ky+1][kx] + wv * pv[ky+1][kx];
                }
            if (oc == sx) {
                if (g0 == sy) qpix[ch] = q0;
                if (g1 == sy) qpix[ch] = q1;
            }
            float ls = q0 + q1, lq = q0*q0 + q1*q1;
            #pragma unroll
            for (int off = 32; off > 0; off >>= 1) {
                ls += __shfl_down(ls, off);
                lq += __shfl_down(lq, off);
            }
            if ((t & 63) == 0) {
                atomicAdd(&sRed[ch][0], ls);
                atomicAdd(&sRed[ch][1], lq);
            }
        }
        __syncthreads();
        if (t < 10) {
            atomicAdd(wsm + 512 + t, sRed[t][0]);
            atomicAdd(wsm + 528 + t, sRed[t][1]);
        }
    }
    // keep sPad alive
    if (t == 1023 && sPad[0] != 0.f) wsm[2175] = sPad[0];
}

__global__ void k_final(const float* __restrict__ ws,
                        const float* __restrict__ gamma,
                        const float* __restrict__ beta,
                        const float* __restrict__ w1,
                        const float* __restrict__ w2,
                        float* __restrict__ out) {
    int n = threadIdx.x;
    if (n >= 128) return;
    const float inv = 1.f / 524288.f;
    float qn[10];
    for (int c = 0; c < 10; ++c) {
        float mean = ws[512 + c] * inv;
        float var  = ws[528 + c] * inv - mean * mean;
        float q    = ws[544 + n * 10 + c];
        qn[c] = (q - mean) * rsqrtf(var + 1e-5f) * gamma[c] + beta[c];
    }
    float a = 0.f;
    for (int c = 0; c < 10; ++c) a += qn[c] * w1[c];
    a = fmaxf(a, 0.f);
    float b[8], mb = 0.f;
    for (int j = 0; j < 8; ++j) {
        float bj = 0.f;
        for (int c = 0; c < 10; ++c) bj += qn[c] * w2[j * 10 + c];
        bj = fmaxf(bj, 0.f);
        b[j] = bj;
        mb += bj;
    }
    mb *= 0.125f;
    for (int j = 0; j < 8; ++j) out[n * 8 + j] = a + b[j] - mb;
}

extern "C" void kernel_launch(void* const* d_in, const int* in_sizes, int n_in,
                              void* d_out, int out_size, void* d_ws, size_t ws_size,
                              hipStream_t stream) {
    const float* X         = (const float*)d_in[0];
    const int*   S1        = (const int*)  d_in[1];
    const int*   S2        = (const int*)  d_in[2];
    const float* conv_h_w  = (const float*)d_in[3];
    const float* conv_r_w  = (const float*)d_in[4];
    const float* conv_q_ws = (const float*)d_in[5];
    const float* bn_gamma  = (const float*)d_in[6];
    const float* bn_beta   = (const float*)d_in[7];
    const float* duel_w1   = (const float*)d_in[8];
    const float* duel_w2   = (const float*)d_in[9];
    const float* vi_h_w    = (const float*)d_in[10];
    const float* vi_r_w    = (const float*)d_in[11];
    const float* vi_q_ws   = (const float*)d_in[12];
    float* ws = (float*)d_ws;

    k_precomp<<<1, 512, 0, stream>>>(conv_h_w, conv_r_w, vi_h_w, vi_r_w, ws);
    k_main<<<256, 1024, 0, stream>>>(X, S1, S2, conv_q_ws, vi_q_ws, ws, ws);
    k_final<<<1, 128, 0, stream>>>(ws, bn_gamma, bn_beta, duel_w1, duel_w2, (float*)d_out);
}

// Round 5
// 239.552 us; speedup vs baseline: 1.1599x; 1.1599x over previous
//
#include <hip/hip_runtime.h>

// ---------------------------------------------------------------------------
// HVIN: maxpool -> composite5x5 conv -> VI scan (32^2, redundant per pair) ->
//       upsample -> composite5x5 conv -> VI scan (64^2, split across a block
//       pair with per-step halo exchange) -> final conv + BN + dueling head
//
// Grid: 256 blocks x 1024 threads. Pair (b, b^8) on the SAME XCD handles
// image n = (b&7)|((b>>4)<<3); half = (b>>3)&1 (outer rows [0,32)/[32,64)).
// Outer VI: per-step boundary-row halo exchange through global memory with a
// monotone per-block flag (release/acquire, agent scope). Flags/halos are
// CACHE-LINE PADDED (128 B / 1 KB stride) so each spinner owns its line.
// The sender wave (wave 0) contains the flag thread, so the release-store's
// vmcnt drain publishes the halo: ONE __syncthreads per VI step.
// Flags: outer steps 1..15, vbar 16.
//
// ws layout:
//   floats [0..49] WeffO  [64..225] GO  [256..305] WeffI  [320..481] GI
//   floats [512..521] bn_sum   [528..537] bn_sumsq
//   floats [544..1823] q_pix[128][10]
//   ints   [4096 + bid*32]  flags[256], 128 B apart (zeroed by k_precomp)
//   floats [16384 + bid*256] halo[256][3 slots][64], 1 KB apart
// ---------------------------------------------------------------------------

#define NEG_BIG (-3.402823466e38f)
#define SCOPE_AGENT __HIP_MEMORY_SCOPE_AGENT

__global__ void k_precomp(const float* __restrict__ conv_h_w,
                          const float* __restrict__ conv_r_w,
                          const float* __restrict__ vi_h_w,
                          const float* __restrict__ vi_r_w,
                          float* __restrict__ ws) {
    __shared__ float sG[2][162];
    int t = threadIdx.x; // 512 threads
    if (t < 324) {
        int set = t / 162;      // 0 = outer, 1 = inner
        int e   = t % 162;
        int ax = e % 3;  int e1 = e / 3;
        int ay = e1 % 3; int e2 = e1 / 3;
        int i  = e2 % 2; int e3 = e2 / 2;
        int bx = e3 % 3; int by = e3 / 3;
        const float* Wh = set ? vi_h_w : conv_h_w;
        const float* Wr = set ? vi_r_w : conv_r_w;
        float acc = 0.f;
        for (int c = 0; c < 150; ++c)
            acc += Wr[(c*3+by)*3+bx] * Wh[((c*2+i)*3+ay)*3+ax];
        sG[set][e] = acc;
        ws[(set ? 320 : 64) + e] = acc;
    }
    if (t >= 480 && t < 512) ws[512 + (t - 480)] = 0.f;   // zero BN accumulators
    for (int i = t; i < 8192; i += 512) ((int*)ws)[4096 + i] = 0;  // flags
    __syncthreads();
    if (t < 100) {
        int set = t / 50;
        int e   = t % 50;
        int i  = e / 25;
        int oy = (e % 25) / 5;
        int ox = e % 5;
        float acc = 0.f;
        for (int by = 0; by < 3; ++by) {
            int ay = oy - by; if (ay < 0 || ay > 2) continue;
            for (int bx = 0; bx < 3; ++bx) {
                int ax = ox - bx; if (ax < 0 || ax > 2) continue;
                acc += sG[set][(((by*3+bx)*2+i)*3+ay)*3+ax];
            }
        }
        ws[(set ? 256 : 0) + e] = acc;
    }
}

// ---- inner VI step: 1024 threads, full 32x32 grid, no exchange -----------
#define ISTEP(VC, VN, K)                                                      \
  {                                                                           \
    const float* wk_ = vi_q_ws + (K) * 180;                                   \
    float pv_[3][3];                                                          \
    _Pragma("unroll") for (int dy = 0; dy < 3; ++dy)                          \
      _Pragma("unroll") for (int dx = 0; dx < 3; ++dx)                        \
        pv_[dy][dx] = VC[iy + dy][ix + dx];                                   \
    float m_ = NEG_BIG;                                                       \
    for (int ch = 0; ch < 10; ++ch) {                                         \
      const float* wc_ = wk_ + ch * 18;                                       \
      float q_ = 0.f;                                                         \
      _Pragma("unroll") for (int ky = 0; ky < 3; ++ky)                        \
        _Pragma("unroll") for (int kx = 0; kx < 3; ++kx)                      \
          q_ += wc_[ky*3+kx] * prI[ky][kx] + wc_[9+ky*3+kx] * pv_[ky][kx];    \
      m_ = fmaxf(m_, q_);                                                     \
    }                                                                         \
    VN[1 + iy][1 + ix] = m_;                                                  \
    isum += m_;                                                               \
    __syncthreads();                                                          \
  }

// ---- outer VI step: wave rp handles local row pair (2pp, 2pp+1) ----------
#define OSTEP(VC, VN, K)                                                      \
  {                                                                           \
    const float* wk_ = conv_q_ws + (K) * 270;                                 \
    float pv_[4][3];                                                          \
    _Pragma("unroll") for (int dy = 0; dy < 4; ++dy)                          \
      _Pragma("unroll") for (int dx = 0; dx < 3; ++dx)                        \
        pv_[dy][dx] = VC[2*pp + dy][oc + dx];                                 \
    float vm0_ = NEG_BIG, vm1_ = NEG_BIG;                                     \
    for (int ch = 0; ch < 10; ++ch) {                                         \
      const float* wc_ = wk_ + ch * 27;                                       \
      float q0_ = 0.f, q1_ = 0.f;                                             \
      _Pragma("unroll") for (int ky = 0; ky < 3; ++ky)                        \
        _Pragma("unroll") for (int kx = 0; kx < 3; ++kx) {                    \
          float wm_ = wc_[ky*3+kx], wr_ = wc_[9+ky*3+kx], wv_ = wc_[18+ky*3+kx]; \
          q0_ += wm_*pmO[ky][kx]   + wr_*pqO[ky][kx]   + wv_*pv_[ky][kx];     \
          q1_ += wm_*pmO[ky+1][kx] + wr_*pqO[ky+1][kx] + wv_*pv_[ky+1][kx];   \
        }                                                                     \
      vm0_ = fmaxf(vm0_, q0_); vm1_ = fmaxf(vm1_, q1_);                       \
    }                                                                         \
    VN[1+2*pp][1+oc] = vm0_;                                                  \
    VN[2+2*pp][1+oc] = vm1_;                                                  \
    os0 += vm0_; os1 += vm1_;                                                 \
    if ((K) < 15 && rp == 0) {                                                \
      __hip_atomic_store(ghMine + ((K)&1)*64 + oc, half ? vm0_ : vm1_,        \
                         __ATOMIC_RELAXED, SCOPE_AGENT);                      \
      if (t == 0) {                                                           \
        __hip_atomic_store(flagMine, (K) + 1, __ATOMIC_RELEASE, SCOPE_AGENT); \
        int spins_ = 0;                                                       \
        while (__hip_atomic_load(flagPart, __ATOMIC_ACQUIRE, SCOPE_AGENT) < (K)+1) \
          if (++spins_ > (1 << 27)) break;                                    \
      }                                                                       \
      VN[gRowO][1+oc] =                                                       \
        __hip_atomic_load(ghPart + ((K)&1)*64 + oc,                           \
                          __ATOMIC_RELAXED, SCOPE_AGENT);                     \
    }                                                                         \
    __syncthreads();                                                          \
  }

__global__ __launch_bounds__(1024) void k_main(
    const float* __restrict__ Xg,        // [128][2][64][64]
    const int*   __restrict__ S1,
    const int*   __restrict__ S2,
    const float* __restrict__ conv_q_ws, // [16][10][3][3][3]
    const float* __restrict__ vi_q_ws,   // [16][10][2][3][3]
    const float* __restrict__ ws,        // composites (read-only)
    float*       __restrict__ wsm)       // BN accum + qpix + flags + halo
{
    __shared__ float sX[2][64][64];
    __shared__ float sX1[2][32][32];
    __shared__ float sr1[34][34];        // ring-padded r1, later v1
    __shared__ float sva[34][34];        // inner v ping
    __shared__ float svb[34][34];        // inner v pong
    __shared__ float sm[34][66];         // rows gr0-1..gr0+32, ring-padded
    __shared__ float sr[34][66];
    __shared__ float sV0[34][66];
    __shared__ float sV1[34][66];
    __shared__ float sRed[10][2];
    // LDS total ~88.7 KB > 80 KB -> exactly 1 block/CU (pair co-residency)

    const int bid  = blockIdx.x;
    const int half = (bid >> 3) & 1;
    const int n    = (bid & 7) | ((bid >> 4) << 3);  // pair (b, b^8) same XCD
    const int gr0  = half << 5;          // first own outer row
    const int t    = threadIdx.x;

    int*   flagMine = (int*)wsm + 4096 + bid * 32;        // 128 B apart
    int*   flagPart = (int*)wsm + 4096 + (bid ^ 8) * 32;
    float* ghMine   = wsm + 16384 + bid * 256;            // 1 KB apart
    float* ghPart   = wsm + 16384 + (bid ^ 8) * 256;
    const int gRowO = half ? 0 : 33;     // outer ghost array row

    // ---- zero-init ring/halo borders (never written again) ----
    {
        float* z;
        z = &sr1[0][0]; for (int i = t; i < 1156; i += 1024) z[i] = 0.f;
        z = &sva[0][0]; for (int i = t; i < 1156; i += 1024) z[i] = 0.f;
        z = &svb[0][0]; for (int i = t; i < 1156; i += 1024) z[i] = 0.f;
        z = &sm[0][0];  for (int i = t; i < 2244; i += 1024) z[i] = 0.f;
        z = &sr[0][0];  for (int i = t; i < 2244; i += 1024) z[i] = 0.f;
        z = &sV0[0][0]; for (int i = t; i < 2244; i += 1024) z[i] = 0.f;
        z = &sV1[0][0]; for (int i = t; i < 2244; i += 1024) z[i] = 0.f;
    }
    // ---- P0: load full X (coalesced float4) ----
    {
        const float4* src = (const float4*)(Xg + (size_t)n * 8192);
        float4* dst = (float4*)&sX[0][0][0];
        dst[t] = src[t];
        dst[t + 1024] = src[t + 1024];
    }
    __syncthreads();

    // ---- P1: maxpool 2x2 -> sX1 ----
    for (int idx = t; idx < 2048; idx += 1024) {
        int c = idx >> 10;
        int y = (idx >> 5) & 31;
        int x = idx & 31;
        float a0 = sX[c][2*y][2*x],   a1 = sX[c][2*y][2*x+1];
        float a2 = sX[c][2*y+1][2*x], a3 = sX[c][2*y+1][2*x+1];
        sX1[c][y][x] = fmaxf(fmaxf(a0, a1), fmaxf(a2, a3));
    }
    __syncthreads();

    // ---- P2: r1 = composite 5x5 conv(X1) + border correction (redundant) ----
    const int iy = t >> 5, ix = t & 31;   // 1 px/thread on the 32x32 grid
    {
        const float* WeffI = ws + 256;
        const float* GI    = ws + 320;
        float acc = 0.f;
        for (int i = 0; i < 2; ++i)
            for (int oy = 0; oy < 5; ++oy) {
                int yy = iy + oy - 2; if (yy < 0 || yy >= 32) continue;
                for (int ox = 0; ox < 5; ++ox) {
                    int xx = ix + ox - 2; if (xx < 0 || xx >= 32) continue;
                    acc += WeffI[i*25 + oy*5 + ox] * sX1[i][yy][xx];
                }
            }
        if (iy == 0 || iy == 31 || ix == 0 || ix == 31) {
            float corr = 0.f;
            for (int by = 0; by < 3; ++by)
                for (int bx = 0; bx < 3; ++bx) {
                    int qy = iy + by - 1, qx = ix + bx - 1;
                    if (qy >= 0 && qy < 32 && qx >= 0 && qx < 32) continue;
                    const float* Gb = GI + (by*3+bx)*18;
                    for (int i = 0; i < 2; ++i)
                        for (int ay = 0; ay < 3; ++ay) {
                            int yy2 = qy + ay - 1; if (yy2 < 0 || yy2 >= 32) continue;
                            for (int ax = 0; ax < 3; ++ax) {
                                int xx2 = qx + ax - 1; if (xx2 < 0 || xx2 >= 32) continue;
                                corr += Gb[i*9 + ay*3 + ax] * sX1[i][yy2][xx2];
                            }
                        }
                }
            acc -= corr;
        }
        sr1[1+iy][1+ix] = acc;
    }
    __syncthreads();

    // ---- P3: inner VI loop (16 steps, full grid, redundant per pair) ----
    {
        float prI[3][3];
        #pragma unroll
        for (int dy = 0; dy < 3; ++dy)
            #pragma unroll
            for (int dx = 0; dx < 3; ++dx)
                prI[dy][dx] = sr1[iy+dy][ix+dx];
        float isum = 0.f;
        for (int k2 = 0; k2 < 8; ++k2) {
            ISTEP(sva, svb, 2*k2);
            ISTEP(svb, sva, 2*k2+1);
        }
        sr1[1+iy][1+ix] = isum * 0.25f;   // v1 overwrites r1
    }
    __syncthreads();

    // ---- P4+P5: m = upsample(v1), r = composite conv(X); rows gr0-1..gr0+32
    {
        const float* WeffO = ws;
        const float* GO    = ws + 64;
        int c = t & 63;
        for (int ar = t >> 6; ar < 34; ar += 16) {
            int g = gr0 + ar - 1;
            if ((unsigned)g < 64u) {
                // bilinear upsample 32->64 at (g, c)
                int y0, y1; float wy0, wy1;
                if ((g & 1) == 0) { y1 = g >> 1; y0 = (y1 > 0) ? y1 - 1 : 0; wy1 = 0.75f; wy0 = 0.25f; }
                else              { y0 = g >> 1; y1 = (y0 < 31) ? y0 + 1 : 31; wy0 = 0.75f; wy1 = 0.25f; }
                int xa, xb; float wx0, wx1;
                if ((c & 1) == 0) { xb = c >> 1; xa = (xb > 0) ? xb - 1 : 0; wx1 = 0.75f; wx0 = 0.25f; }
                else              { xa = c >> 1; xb = (xa < 31) ? xa + 1 : 31; wx0 = 0.75f; wx1 = 0.25f; }
                sm[ar][1+c] = wy0 * (wx0 * sr1[1+y0][1+xa] + wx1 * sr1[1+y0][1+xb])
                            + wy1 * (wx0 * sr1[1+y1][1+xa] + wx1 * sr1[1+y1][1+xb]);
                // composite 5x5 conv of X at (g, c)
                float acc = 0.f;
                for (int i = 0; i < 2; ++i)
                    for (int oy = 0; oy < 5; ++oy) {
                        int yy = g + oy - 2; if (yy < 0 || yy >= 64) continue;
                        for (int ox = 0; ox < 5; ++ox) {
                            int xx = c + ox - 2; if (xx < 0 || xx >= 64) continue;
                            acc += WeffO[i*25 + oy*5 + ox] * sX[i][yy][xx];
                        }
                    }
                if (g == 0 || g == 63 || c == 0 || c == 63) {
                    float corr = 0.f;
                    for (int by = 0; by < 3; ++by)
                        for (int bx = 0; bx < 3; ++bx) {
                            int qy = g + by - 1, qx = c + bx - 1;
                            if (qy >= 0 && qy < 64 && qx >= 0 && qx < 64) continue;
                            const float* Gb = GO + (by*3+bx)*18;
                            for (int i = 0; i < 2; ++i)
                                for (int ay = 0; ay < 3; ++ay) {
                                    int yy2 = qy + ay - 1; if (yy2 < 0 || yy2 >= 64) continue;
                                    for (int ax = 0; ax < 3; ++ax) {
                                        int xx2 = qx + ax - 1; if (xx2 < 0 || xx2 >= 64) continue;
                                        corr += Gb[i*9 + ay*3 + ax] * sX[i][yy2][xx2];
                                    }
                                }
                        }
                    acc -= corr;
                }
                sr[ar][1+c] = acc;
            }
        }
    }
    __syncthreads();

    // ---- P6: outer VI loop (16 steps). Wave 0 owns the boundary row pair.
    const int rp = t >> 6;                   // wave id
    const int pp = half ? rp : (15 - rp);    // local row-pair index
    const int oc = t & 63;                   // col

    float pmO[4][3], pqO[4][3];              // step-invariant patches (hoisted)
    #pragma unroll
    for (int dy = 0; dy < 4; ++dy)
        #pragma unroll
        for (int dx = 0; dx < 3; ++dx) {
            pmO[dy][dx] = sm[2*pp+dy][oc+dx];
            pqO[dy][dx] = sr[2*pp+dy][oc+dx];
        }

    float os0 = 0.f, os1 = 0.f;
    for (int k2 = 0; k2 < 8; ++k2) {
        OSTEP(sV0, sV1, 2*k2);
        OSTEP(sV1, sV0, 2*k2+1);
    }

    // ---- vbar = sum/16 into sV1; exchange its halo (slot 2, flag 16) ----
    {
        float vb0 = os0 * 0.0625f, vb1 = os1 * 0.0625f;
        sV1[1+2*pp][1+oc] = vb0;
        sV1[2+2*pp][1+oc] = vb1;
        if (rp == 0) {
            __hip_atomic_store(ghMine + 128 + oc, half ? vb0 : vb1,
                               __ATOMIC_RELAXED, SCOPE_AGENT);
            if (t == 0) {
                __hip_atomic_store(flagMine, 16, __ATOMIC_RELEASE, SCOPE_AGENT);
                int spins = 0;
                while (__hip_atomic_load(flagPart, __ATOMIC_ACQUIRE, SCOPE_AGENT) < 16)
                    if (++spins > (1 << 27)) break;
            }
            sV1[gRowO][1+oc] =
                __hip_atomic_load(ghPart + 128 + oc, __ATOMIC_RELAXED, SCOPE_AGENT);
        }
        if (t >= 64 && t < 84) ((float*)sRed)[t - 64] = 0.f;
    }
    __syncthreads();

    // ---- P7: final conv (w15) on {m, r, vbar} + BN stats + (S1,S2) pick ----
    {
        const float* wk = conv_q_ws + 15 * 270;
        float pv[4][3];
        #pragma unroll
        for (int dy = 0; dy < 4; ++dy)
            #pragma unroll
            for (int dx = 0; dx < 3; ++dx)
                pv[dy][dx] = sV1[2*pp+dy][oc+dx];
        int sy = S1[n], sx = S2[n];
        int g0 = gr0 + 2*pp, g1 = g0 + 1;
        float* qpix = wsm + 544 + n * 10;
        for (int ch = 0; ch < 10; ++ch) {
            const float* wc = wk + ch * 27;
            float q0 = 0.f, q1 = 0.f;
            #pragma unroll
            for (int ky = 0; ky < 3; ++ky)
                #pragma unroll
                for (int kx = 0; kx < 3; ++kx) {
                    float wm = wc[ky*3+kx];
                    float wr = wc[9  + ky*3+kx];
                    float wv = wc[18 + ky*3+kx];
                    q0 += wm * pmO[ky][kx]   + wr * pqO[ky][kx]   + wv * pv[ky][kx];
                    q1 += wm * pmO[ky+1][kx] + wr * pqO[ky+1][kx] + wv * pv[ky+1][kx];
                }
            if (oc == sx) {
                if (g0 == sy) qpix[ch] = q0;
                if (g1 == sy) qpix[ch] = q1;
            }
            float ls = q0 + q1, lq = q0*q0 + q1*q1;
            #pragma unroll
            for (int off = 32; off > 0; off >>= 1) {
                ls += __shfl_down(ls, off);
                lq += __shfl_down(lq, off);
            }
            if ((t & 63) == 0) {
                atomicAdd(&sRed[ch][0], ls);
                atomicAdd(&sRed[ch][1], lq);
            }
        }
        __syncthreads();
        if (t < 10) {
            atomicAdd(wsm + 512 + t, sRed[t][0]);
            atomicAdd(wsm + 528 + t, sRed[t][1]);
        }
    }
}

__global__ void k_final(const float* __restrict__ ws,
                        const float* __restrict__ gamma,
                        const float* __restrict__ beta,
                        const float* __restrict__ w1,
                        const float* __restrict__ w2,
                        float* __restrict__ out) {
    int n = threadIdx.x;
    if (n >= 128) return;
    const float inv = 1.f / 524288.f;
    float qn[10];
    for (int c = 0; c < 10; ++c) {
        float mean = ws[512 + c] * inv;
        float var  = ws[528 + c] * inv - mean * mean;
        float q    = ws[544 + n * 10 + c];
        qn[c] = (q - mean) * rsqrtf(var + 1e-5f) * gamma[c] + beta[c];
    }
    float a = 0.f;
    for (int c = 0; c < 10; ++c) a += qn[c] * w1[c];
    a = fmaxf(a, 0.f);
    float b[8], mb = 0.f;
    for (int j = 0; j < 8; ++j) {
        float bj = 0.f;
        for (int c = 0; c < 10; ++c) bj += qn[c] * w2[j * 10 + c];
        bj = fmaxf(bj, 0.f);
        b[j] = bj;
        mb += bj;
    }
    mb *= 0.125f;
    for (int j = 0; j < 8; ++j) out[n * 8 + j] = a + b[j] - mb;
}

extern "C" void kernel_launch(void* const* d_in, const int* in_sizes, int n_in,
                              void* d_out, int out_size, void* d_ws, size_t ws_size,
                              hipStream_t stream) {
    const float* X         = (const float*)d_in[0];
    const int*   S1        = (const int*)  d_in[1];
    const int*   S2        = (const int*)  d_in[2];
    const float* conv_h_w  = (const float*)d_in[3];
    const float* conv_r_w  = (const float*)d_in[4];
    const float* conv_q_ws = (const float*)d_in[5];
    const float* bn_gamma  = (const float*)d_in[6];
    const float* bn_beta   = (const float*)d_in[7];
    const float* duel_w1   = (const float*)d_in[8];
    const float* duel_w2   = (const float*)d_in[9];
    const float* vi_h_w    = (const float*)d_in[10];
    const float* vi_r_w    = (const float*)d_in[11];
    const float* vi_q_ws   = (const float*)d_in[12];
    float* ws = (float*)d_ws;

    k_precomp<<<1, 512, 0, stream>>>(conv_h_w, conv_r_w, vi_h_w, vi_r_w, ws);
    k_main<<<256, 1024, 0, stream>>>(X, S1, S2, conv_q_ws, vi_q_ws, ws, ws);
    k_final<<<1, 128, 0, stream>>>(ws, bn_gamma, bn_beta, duel_w1, duel_w2, (float*)d_out);
}

// Round 6
// 237.616 us; speedup vs baseline: 1.1694x; 1.0081x over previous
//
#include <hip/hip_runtime.h>

// ---------------------------------------------------------------------------
// HVIN: maxpool -> composite5x5 conv -> VI scan (32^2, redundant per pair) ->
//       upsample -> composite5x5 conv -> VI scan (64^2, split across a block
//       pair with per-step halo exchange) -> final conv + BN + dueling head
//
// Grid: 256 blocks x 1024 threads. Pair (b, b^8) on the SAME XCD handles
// image n = (b&7)|((b>>4)<<3); half = (b>>3)&1 (outer rows [0,32)/[32,64)).
// Outer VI: per-step boundary-row halo exchange through global memory with a
// monotone per-block flag (release/acquire, agent scope). Flags/halos are
// CACHE-LINE PADDED (128 B / 1 KB stride) so each spinner owns its line.
// The sender wave (wave 0) contains the flag thread, so the release-store's
// vmcnt drain publishes the halo: ONE __syncthreads per VI step.
// Flags: outer steps 1..15, vbar 16.
//
// waves_per_eu(4,4): 16-wave block => exactly 4 waves/EU => 128-VGPR budget;
// lets the hoisted step-invariant patches live in registers with NO spill
// (R5: compiler capped at 64 VGPR -> 11.4 MB scratch write-back).
//
// ws layout:
//   floats [0..49] WeffO  [64..225] GO  [256..305] WeffI  [320..481] GI
//   floats [512..521] bn_sum   [528..537] bn_sumsq
//   floats [544..1823] q_pix[128][10]
//   ints   [4096 + bid*32]  flags[256], 128 B apart (zeroed by k_precomp)
//   floats [16384 + bid*256] halo[256][3 slots][64], 1 KB apart
// ---------------------------------------------------------------------------

#define NEG_BIG (-3.402823466e38f)
#define SCOPE_AGENT __HIP_MEMORY_SCOPE_AGENT

__global__ void k_precomp(const float* __restrict__ conv_h_w,
                          const float* __restrict__ conv_r_w,
                          const float* __restrict__ vi_h_w,
                          const float* __restrict__ vi_r_w,
                          float* __restrict__ ws) {
    __shared__ float sG[2][162];
    int t = threadIdx.x; // 512 threads
    if (t < 324) {
        int set = t / 162;      // 0 = outer, 1 = inner
        int e   = t % 162;
        int ax = e % 3;  int e1 = e / 3;
        int ay = e1 % 3; int e2 = e1 / 3;
        int i  = e2 % 2; int e3 = e2 / 2;
        int bx = e3 % 3; int by = e3 / 3;
        const float* Wh = set ? vi_h_w : conv_h_w;
        const float* Wr = set ? vi_r_w : conv_r_w;
        float acc = 0.f;
        for (int c = 0; c < 150; ++c)
            acc += Wr[(c*3+by)*3+bx] * Wh[((c*2+i)*3+ay)*3+ax];
        sG[set][e] = acc;
        ws[(set ? 320 : 64) + e] = acc;
    }
    if (t >= 480 && t < 512) ws[512 + (t - 480)] = 0.f;   // zero BN accumulators
    for (int i = t; i < 8192; i += 512) ((int*)ws)[4096 + i] = 0;  // flags
    __syncthreads();
    if (t < 100) {
        int set = t / 50;
        int e   = t % 50;
        int i  = e / 25;
        int oy = (e % 25) / 5;
        int ox = e % 5;
        float acc = 0.f;
        for (int by = 0; by < 3; ++by) {
            int ay = oy - by; if (ay < 0 || ay > 2) continue;
            for (int bx = 0; bx < 3; ++bx) {
                int ax = ox - bx; if (ax < 0 || ax > 2) continue;
                acc += sG[set][(((by*3+bx)*2+i)*3+ay)*3+ax];
            }
        }
        ws[(set ? 256 : 0) + e] = acc;
    }
}

// ---- inner VI step: 1024 threads, full 32x32 grid, no exchange -----------
// ch loop fully unrolled: all weight offsets compile-time -> batched s_load.
#define ISTEP(VC, VN, K)                                                      \
  {                                                                           \
    const float* wk_ = vi_q_ws + (K) * 180;                                   \
    float pv_[3][3];                                                          \
    _Pragma("unroll") for (int dy = 0; dy < 3; ++dy)                          \
      _Pragma("unroll") for (int dx = 0; dx < 3; ++dx)                        \
        pv_[dy][dx] = VC[iy + dy][ix + dx];                                   \
    float m_ = NEG_BIG;                                                       \
    _Pragma("unroll") for (int ch = 0; ch < 10; ++ch) {                       \
      const float* wc_ = wk_ + ch * 18;                                       \
      float q_ = 0.f;                                                         \
      _Pragma("unroll") for (int ky = 0; ky < 3; ++ky)                        \
        _Pragma("unroll") for (int kx = 0; kx < 3; ++kx)                      \
          q_ += wc_[ky*3+kx] * prI[ky][kx] + wc_[9+ky*3+kx] * pv_[ky][kx];    \
      m_ = fmaxf(m_, q_);                                                     \
    }                                                                         \
    VN[1 + iy][1 + ix] = m_;                                                  \
    isum += m_;                                                               \
    __syncthreads();                                                          \
  }

// ---- outer VI step: wave rp handles local row pair (2pp, 2pp+1) ----------
#define OSTEP(VC, VN, K)                                                      \
  {                                                                           \
    const float* wk_ = conv_q_ws + (K) * 270;                                 \
    float pv_[4][3];                                                          \
    _Pragma("unroll") for (int dy = 0; dy < 4; ++dy)                          \
      _Pragma("unroll") for (int dx = 0; dx < 3; ++dx)                        \
        pv_[dy][dx] = VC[2*pp + dy][oc + dx];                                 \
    float vm0_ = NEG_BIG, vm1_ = NEG_BIG;                                     \
    _Pragma("unroll") for (int ch = 0; ch < 10; ++ch) {                       \
      const float* wc_ = wk_ + ch * 27;                                       \
      float q0_ = 0.f, q1_ = 0.f;                                             \
      _Pragma("unroll") for (int ky = 0; ky < 3; ++ky)                        \
        _Pragma("unroll") for (int kx = 0; kx < 3; ++kx) {                    \
          float wm_ = wc_[ky*3+kx], wr_ = wc_[9+ky*3+kx], wv_ = wc_[18+ky*3+kx]; \
          q0_ += wm_*pmO[ky][kx]   + wr_*pqO[ky][kx]   + wv_*pv_[ky][kx];     \
          q1_ += wm_*pmO[ky+1][kx] + wr_*pqO[ky+1][kx] + wv_*pv_[ky+1][kx];   \
        }                                                                     \
      vm0_ = fmaxf(vm0_, q0_); vm1_ = fmaxf(vm1_, q1_);                       \
    }                                                                         \
    VN[1+2*pp][1+oc] = vm0_;                                                  \
    VN[2+2*pp][1+oc] = vm1_;                                                  \
    os0 += vm0_; os1 += vm1_;                                                 \
    if ((K) < 15 && rp == 0) {                                                \
      __hip_atomic_store(ghMine + ((K)&1)*64 + oc, half ? vm0_ : vm1_,        \
                         __ATOMIC_RELAXED, SCOPE_AGENT);                      \
      if (t == 0) {                                                           \
        __hip_atomic_store(flagMine, (K) + 1, __ATOMIC_RELEASE, SCOPE_AGENT); \
        int spins_ = 0;                                                       \
        while (__hip_atomic_load(flagPart, __ATOMIC_ACQUIRE, SCOPE_AGENT) < (K)+1) \
          if (++spins_ > (1 << 27)) break;                                    \
      }                                                                       \
      VN[gRowO][1+oc] =                                                       \
        __hip_atomic_load(ghPart + ((K)&1)*64 + oc,                           \
                          __ATOMIC_RELAXED, SCOPE_AGENT);                     \
    }                                                                         \
    __syncthreads();                                                          \
  }

__global__ __launch_bounds__(1024)
__attribute__((amdgpu_waves_per_eu(4, 4)))
void k_main(
    const float* __restrict__ Xg,        // [128][2][64][64]
    const int*   __restrict__ S1,
    const int*   __restrict__ S2,
    const float* __restrict__ conv_q_ws, // [16][10][3][3][3]
    const float* __restrict__ vi_q_ws,   // [16][10][2][3][3]
    const float* __restrict__ ws,        // composites (read-only)
    float*       __restrict__ wsm)       // BN accum + qpix + flags + halo
{
    __shared__ float sX[2][64][64];
    __shared__ float sX1[2][32][32];
    __shared__ float sr1[34][34];        // ring-padded r1, later v1
    __shared__ float sva[34][34];        // inner v ping
    __shared__ float svb[34][34];        // inner v pong
    __shared__ float sm[34][66];         // rows gr0-1..gr0+32, ring-padded
    __shared__ float sr[34][66];
    __shared__ float sV0[34][66];
    __shared__ float sV1[34][66];
    __shared__ float sRed[10][2];
    // LDS total ~88.7 KB > 80 KB -> exactly 1 block/CU (pair co-residency)

    const int bid  = blockIdx.x;
    const int half = (bid >> 3) & 1;
    const int n    = (bid & 7) | ((bid >> 4) << 3);  // pair (b, b^8) same XCD
    const int gr0  = half << 5;          // first own outer row
    const int t    = threadIdx.x;

    int*   flagMine = (int*)wsm + 4096 + bid * 32;        // 128 B apart
    int*   flagPart = (int*)wsm + 4096 + (bid ^ 8) * 32;
    float* ghMine   = wsm + 16384 + bid * 256;            // 1 KB apart
    float* ghPart   = wsm + 16384 + (bid ^ 8) * 256;
    const int gRowO = half ? 0 : 33;     // outer ghost array row

    // ---- zero-init ring/halo borders (never written again) ----
    {
        float* z;
        z = &sr1[0][0]; for (int i = t; i < 1156; i += 1024) z[i] = 0.f;
        z = &sva[0][0]; for (int i = t; i < 1156; i += 1024) z[i] = 0.f;
        z = &svb[0][0]; for (int i = t; i < 1156; i += 1024) z[i] = 0.f;
        z = &sm[0][0];  for (int i = t; i < 2244; i += 1024) z[i] = 0.f;
        z = &sr[0][0];  for (int i = t; i < 2244; i += 1024) z[i] = 0.f;
        z = &sV0[0][0]; for (int i = t; i < 2244; i += 1024) z[i] = 0.f;
        z = &sV1[0][0]; for (int i = t; i < 2244; i += 1024) z[i] = 0.f;
    }
    // ---- P0: load full X (coalesced float4) ----
    {
        const float4* src = (const float4*)(Xg + (size_t)n * 8192);
        float4* dst = (float4*)&sX[0][0][0];
        dst[t] = src[t];
        dst[t + 1024] = src[t + 1024];
    }
    __syncthreads();

    // ---- P1: maxpool 2x2 -> sX1 ----
    for (int idx = t; idx < 2048; idx += 1024) {
        int c = idx >> 10;
        int y = (idx >> 5) & 31;
        int x = idx & 31;
        float a0 = sX[c][2*y][2*x],   a1 = sX[c][2*y][2*x+1];
        float a2 = sX[c][2*y+1][2*x], a3 = sX[c][2*y+1][2*x+1];
        sX1[c][y][x] = fmaxf(fmaxf(a0, a1), fmaxf(a2, a3));
    }
    __syncthreads();

    // ---- P2: r1 = composite 5x5 conv(X1) + border correction (redundant) ----
    const int iy = t >> 5, ix = t & 31;   // 1 px/thread on the 32x32 grid
    {
        const float* WeffI = ws + 256;
        const float* GI    = ws + 320;
        float acc = 0.f;
        for (int i = 0; i < 2; ++i)
            for (int oy = 0; oy < 5; ++oy) {
                int yy = iy + oy - 2; if (yy < 0 || yy >= 32) continue;
                for (int ox = 0; ox < 5; ++ox) {
                    int xx = ix + ox - 2; if (xx < 0 || xx >= 32) continue;
                    acc += WeffI[i*25 + oy*5 + ox] * sX1[i][yy][xx];
                }
            }
        if (iy == 0 || iy == 31 || ix == 0 || ix == 31) {
            float corr = 0.f;
            for (int by = 0; by < 3; ++by)
                for (int bx = 0; bx < 3; ++bx) {
                    int qy = iy + by - 1, qx = ix + bx - 1;
                    if (qy >= 0 && qy < 32 && qx >= 0 && qx < 32) continue;
                    const float* Gb = GI + (by*3+bx)*18;
                    for (int i = 0; i < 2; ++i)
                        for (int ay = 0; ay < 3; ++ay) {
                            int yy2 = qy + ay - 1; if (yy2 < 0 || yy2 >= 32) continue;
                            for (int ax = 0; ax < 3; ++ax) {
                                int xx2 = qx + ax - 1; if (xx2 < 0 || xx2 >= 32) continue;
                                corr += Gb[i*9 + ay*3 + ax] * sX1[i][yy2][xx2];
                            }
                        }
                }
            acc -= corr;
        }
        sr1[1+iy][1+ix] = acc;
    }
    __syncthreads();

    // ---- P3: inner VI loop (16 steps, full grid, redundant per pair) ----
    {
        float prI[3][3];
        #pragma unroll
        for (int dy = 0; dy < 3; ++dy)
            #pragma unroll
            for (int dx = 0; dx < 3; ++dx)
                prI[dy][dx] = sr1[iy+dy][ix+dx];
        float isum = 0.f;
        for (int k2 = 0; k2 < 8; ++k2) {
            ISTEP(sva, svb, 2*k2);
            ISTEP(svb, sva, 2*k2+1);
        }
        sr1[1+iy][1+ix] = isum * 0.25f;   // v1 overwrites r1
    }
    __syncthreads();

    // ---- P4+P5: m = upsample(v1), r = composite conv(X); rows gr0-1..gr0+32
    {
        const float* WeffO = ws;
        const float* GO    = ws + 64;
        int c = t & 63;
        for (int ar = t >> 6; ar < 34; ar += 16) {
            int g = gr0 + ar - 1;
            if ((unsigned)g < 64u) {
                // bilinear upsample 32->64 at (g, c)
                int y0, y1; float wy0, wy1;
                if ((g & 1) == 0) { y1 = g >> 1; y0 = (y1 > 0) ? y1 - 1 : 0; wy1 = 0.75f; wy0 = 0.25f; }
                else              { y0 = g >> 1; y1 = (y0 < 31) ? y0 + 1 : 31; wy0 = 0.75f; wy1 = 0.25f; }
                int xa, xb; float wx0, wx1;
                if ((c & 1) == 0) { xb = c >> 1; xa = (xb > 0) ? xb - 1 : 0; wx1 = 0.75f; wx0 = 0.25f; }
                else              { xa = c >> 1; xb = (xa < 31) ? xa + 1 : 31; wx0 = 0.75f; wx1 = 0.25f; }
                sm[ar][1+c] = wy0 * (wx0 * sr1[1+y0][1+xa] + wx1 * sr1[1+y0][1+xb])
                            + wy1 * (wx0 * sr1[1+y1][1+xa] + wx1 * sr1[1+y1][1+xb]);
                // composite 5x5 conv of X at (g, c)
                float acc = 0.f;
                for (int i = 0; i < 2; ++i)
                    for (int oy = 0; oy < 5; ++oy) {
                        int yy = g + oy - 2; if (yy < 0 || yy >= 64) continue;
                        for (int ox = 0; ox < 5; ++ox) {
                            int xx = c + ox - 2; if (xx < 0 || xx >= 64) continue;
                            acc += WeffO[i*25 + oy*5 + ox] * sX[i][yy][xx];
                        }
                    }
                if (g == 0 || g == 63 || c == 0 || c == 63) {
                    float corr = 0.f;
                    for (int by = 0; by < 3; ++by)
                        for (int bx = 0; bx < 3; ++bx) {
                            int qy = g + by - 1, qx = c + bx - 1;
                            if (qy >= 0 && qy < 64 && qx >= 0 && qx < 64) continue;
                            const float* Gb = GO + (by*3+bx)*18;
                            for (int i = 0; i < 2; ++i)
                                for (int ay = 0; ay < 3; ++ay) {
                                    int yy2 = qy + ay - 1; if (yy2 < 0 || yy2 >= 64) continue;
                                    for (int ax = 0; ax < 3; ++ax) {
                                        int xx2 = qx + ax - 1; if (xx2 < 0 || xx2 >= 64) continue;
                                        corr += Gb[i*9 + ay*3 + ax] * sX[i][yy2][xx2];
                                    }
                                }
                        }
                    acc -= corr;
                }
                sr[ar][1+c] = acc;
            }
        }
    }
    __syncthreads();

    // ---- P6: outer VI loop (16 steps). Wave 0 owns the boundary row pair.
    const int rp = t >> 6;                   // wave id
    const int pp = half ? rp : (15 - rp);    // local row-pair index
    const int oc = t & 63;                   // col

    float pmO[4][3], pqO[4][3];              // step-invariant patches (hoisted)
    #pragma unroll
    for (int dy = 0; dy < 4; ++dy)
        #pragma unroll
        for (int dx = 0; dx < 3; ++dx) {
            pmO[dy][dx] = sm[2*pp+dy][oc+dx];
            pqO[dy][dx] = sr[2*pp+dy][oc+dx];
        }

    float os0 = 0.f, os1 = 0.f;
    for (int k2 = 0; k2 < 8; ++k2) {
        OSTEP(sV0, sV1, 2*k2);
        OSTEP(sV1, sV0, 2*k2+1);
    }

    // ---- vbar = sum/16 into sV1; exchange its halo (slot 2, flag 16) ----
    {
        float vb0 = os0 * 0.0625f, vb1 = os1 * 0.0625f;
        sV1[1+2*pp][1+oc] = vb0;
        sV1[2+2*pp][1+oc] = vb1;
        if (rp == 0) {
            __hip_atomic_store(ghMine + 128 + oc, half ? vb0 : vb1,
                               __ATOMIC_RELAXED, SCOPE_AGENT);
            if (t == 0) {
                __hip_atomic_store(flagMine, 16, __ATOMIC_RELEASE, SCOPE_AGENT);
                int spins = 0;
                while (__hip_atomic_load(flagPart, __ATOMIC_ACQUIRE, SCOPE_AGENT) < 16)
                    if (++spins > (1 << 27)) break;
            }
            sV1[gRowO][1+oc] =
                __hip_atomic_load(ghPart + 128 + oc, __ATOMIC_RELAXED, SCOPE_AGENT);
        }
        if (t >= 64 && t < 84) ((float*)sRed)[t - 64] = 0.f;
    }
    __syncthreads();

    // ---- P7: final conv (w15) on {m, r, vbar} + BN stats + (S1,S2) pick ----
    {
        const float* wk = conv_q_ws + 15 * 270;
        float pv[4][3];
        #pragma unroll
        for (int dy = 0; dy < 4; ++dy)
            #pragma unroll
            for (int dx = 0; dx < 3; ++dx)
                pv[dy][dx] = sV1[2*pp+dy][oc+dx];
        int sy = S1[n], sx = S2[n];
        int g0 = gr0 + 2*pp, g1 = g0 + 1;
        float* qpix = wsm + 544 + n * 10;
        #pragma unroll
        for (int ch = 0; ch < 10; ++ch) {
            const float* wc = wk + ch * 27;
            float q0 = 0.f, q1 = 0.f;
            #pragma unroll
            for (int ky = 0; ky < 3; ++ky)
                #pragma unroll
                for (int kx = 0; kx < 3; ++kx) {
                    float wm = wc[ky*3+kx];
                    float wr = wc[9  + ky*3+kx];
                    float wv = wc[18 + ky*3+kx];
                    q0 += wm * pmO[ky][kx]   + wr * pqO[ky][kx]   + wv * pv[ky][kx];
                    q1 += wm * pmO[ky+1][kx] + wr * pqO[ky+1][kx] + wv * pv[ky+1][kx];
                }
            if (oc == sx) {
                if (g0 == sy) qpix[ch] = q0;
                if (g1 == sy) qpix[ch] = q1;
            }
            float ls = q0 + q1, lq = q0*q0 + q1*q1;
            #pragma unroll
            for (int off = 32; off > 0; off >>= 1) {
                ls += __shfl_down(ls, off);
                lq += __shfl_down(lq, off);
            }
            if ((t & 63) == 0) {
                atomicAdd(&sRed[ch][0], ls);
                atomicAdd(&sRed[ch][1], lq);
            }
        }
        __syncthreads();
        if (t < 10) {
            atomicAdd(wsm + 512 + t, sRed[t][0]);
            atomicAdd(wsm + 528 + t, sRed[t][1]);
        }
    }
}

__global__ void k_final(const float* __restrict__ ws,
                        const float* __restrict__ gamma,
                        const float* __restrict__ beta,
                        const float* __restrict__ w1,
                        const float* __restrict__ w2,
                        float* __restrict__ out) {
    int n = threadIdx.x;
    if (n >= 128) return;
    const float inv = 1.f / 524288.f;
    float qn[10];
    for (int c = 0; c < 10; ++c) {
        float mean = ws[512 + c] * inv;
        float var  = ws[528 + c] * inv - mean * mean;
        float q    = ws[544 + n * 10 + c];
        qn[c] = (q - mean) * rsqrtf(var + 1e-5f) * gamma[c] + beta[c];
    }
    float a = 0.f;
    for (int c = 0; c < 10; ++c) a += qn[c] * w1[c];
    a = fmaxf(a, 0.f);
    float b[8], mb = 0.f;
    for (int j = 0; j < 8; ++j) {
        float bj = 0.f;
        for (int c = 0; c < 10; ++c) bj += qn[c] * w2[j * 10 + c];
        bj = fmaxf(bj, 0.f);
        b[j] = bj;
        mb += bj;
    }
    mb *= 0.125f;
    for (int j = 0; j < 8; ++j) out[n * 8 + j] = a + b[j] - mb;
}

extern "C" void kernel_launch(void* const* d_in, const int* in_sizes, int n_in,
                              void* d_out, int out_size, void* d_ws, size_t ws_size,
                              hipStream_t stream) {
    const float* X         = (const float*)d_in[0];
    const int*   S1        = (const int*)  d_in[1];
    const int*   S2        = (const int*)  d_in[2];
    const float* conv_h_w  = (const float*)d_in[3];
    const float* conv_r_w  = (const float*)d_in[4];
    const float* conv_q_ws = (const float*)d_in[5];
    const float* bn_gamma  = (const float*)d_in[6];
    const float* bn_beta   = (const float*)d_in[7];
    const float* duel_w1   = (const float*)d_in[8];
    const float* duel_w2   = (const float*)d_in[9];
    const float* vi_h_w    = (const float*)d_in[10];
    const float* vi_r_w    = (const float*)d_in[11];
    const float* vi_q_ws   = (const float*)d_in[12];
    float* ws = (float*)d_ws;

    k_precomp<<<1, 512, 0, stream>>>(conv_h_w, conv_r_w, vi_h_w, vi_r_w, ws);
    k_main<<<256, 1024, 0, stream>>>(X, S1, S2, conv_q_ws, vi_q_ws, ws, ws);
    k_final<<<1, 128, 0, stream>>>(ws, bn_gamma, bn_beta, duel_w1, duel_w2, (float*)d_out);
}